// Round 6
// baseline (1081.950 us; speedup 1.0000x reference)
//
#include <hip/hip_runtime.h>
#include <hip/hip_bf16.h>
#include <cstdint>

// Problem dims (fixed by the reference)
#define B_   8192
#define D_   1024
#define O_   1024
#define HE_  2048
#define NN_  7     // decision nodes
#define NL_  8     // leaves / experts
#define HR_  32    // router hidden
#define RC_  224   // NN_*HR_
#define K3_  3072  // router split-GEMM K (hi|hi|lo)

typedef __attribute__((ext_vector_type(2))) float f32x2;
typedef __attribute__((ext_vector_type(4))) float f32x4;
typedef __attribute__((ext_vector_type(8))) short bf16x8;
typedef __attribute__((ext_vector_type(4))) unsigned short u16x4;
typedef unsigned short u16;
typedef unsigned int u32;

__device__ __forceinline__ u16 f2bf(float f) {
  __hip_bfloat16 h = __float2bfloat16(f);
  return *reinterpret_cast<u16*>(&h);
}
__device__ __forceinline__ float bf2f(u16 u) {
  u32 v = ((u32)u) << 16;
  return *reinterpret_cast<float*>(&v);
}
__device__ __forceinline__ float gelu_exact(float v) {
  return 0.5f * v * (1.0f + erff(v * 0.7071067811865475f));
}
__device__ __forceinline__ void gload16(const void* g, void* l) {
  __builtin_amdgcn_global_load_lds(
      (const __attribute__((address_space(1))) void*)(uintptr_t)g,
      (__attribute__((address_space(3))) void*)(uintptr_t)l,
      16, 0, 0);
}

// ---- Xb3[b][3072] = [bf16(x) | bf16(x) | bf16(x - bf16(x))] ---------------
__global__ __launch_bounds__(256) void build_xb3_kernel(
    const float* __restrict__ in, u16* __restrict__ out) {
  size_t i = ((size_t)blockIdx.x * 256 + threadIdx.x) * 4;
  size_t row = i >> 10;
  int col = (int)(i & 1023);
  f32x4 f = *reinterpret_cast<const f32x4*>(in + i);
  u16x4 hi, lo;
#pragma unroll
  for (int j = 0; j < 4; j++) {
    hi[j] = f2bf(f[j]);
    lo[j] = f2bf(f[j] - bf2f(hi[j]));
  }
  u16* base = out + row * (size_t)K3_ + col;
  *reinterpret_cast<u16x4*>(base)        = hi;
  *reinterpret_cast<u16x4*>(base + 1024) = hi;
  *reinterpret_cast<u16x4*>(base + 2048) = lo;
}

// ---- Wr3[256][3072]: rows c<224 = [w_hi | w_lo | w_hi] of rW1[n][k][h] ----
__global__ __launch_bounds__(256) void build_wr3_kernel(
    const float* __restrict__ rW1, u16* __restrict__ Wr3) {
  size_t i = ((size_t)blockIdx.x * 256 + threadIdx.x) * 4;  // over 256*3072
  int c = (int)(i / K3_), k = (int)(i % K3_);
  int j = k >> 10, kk = k & 1023;
  u16x4 o;
  if (c < RC_) {
    int node = c >> 5, h = c & 31;
    const float* src = rW1 + ((size_t)node * 1024 + kk) * HR_ + h;
#pragma unroll
    for (int t = 0; t < 4; t++) {
      float f = src[t * HR_];
      u16 hi = f2bf(f);
      o[t] = (j == 1) ? f2bf(f - bf2f(hi)) : hi;
    }
  } else {
    o[0] = 0; o[1] = 0; o[2] = 0; o[3] = 0;
  }
  *reinterpret_cast<u16x4*>(Wr3 + i) = o;
}

// ------------- transpose + cvt: out[c*ldo + r] (+e*out_estride) = in[r][c] --
__global__ __launch_bounds__(256) void transpose_cvt_kernel(
    const float* __restrict__ in, u16* __restrict__ out,
    int R, int C, int ldo, long in_estride, long out_estride) {
  __shared__ __attribute__((aligned(16))) float tile[64][65];
  const float* in_e = in + (long)blockIdx.z * in_estride;
  u16* out_e = out + (long)blockIdx.z * out_estride;
  int t = threadIdx.x;
  int r0 = blockIdx.y * 64, c0 = blockIdx.x * 64;
  int cc = t & 63, rbase = t >> 6;
#pragma unroll
  for (int i = 0; i < 16; i++) {
    int rr = rbase + i * 4;
    tile[rr][cc] = in_e[(long)(r0 + rr) * C + c0 + cc];
  }
  __syncthreads();
  int r2 = (t & 31) * 2, cj = t >> 5;
#pragma unroll
  for (int i = 0; i < 8; i++) {
    int c = cj * 8 + i;
    u32 u = (u32)f2bf(tile[r2][c]) | ((u32)f2bf(tile[r2 + 1][c]) << 16);
    *reinterpret_cast<u32*>(out_e + (long)(c0 + c) * ldo + r0 + r2) = u;
  }
}

// ---- router GEMM (m97 128x128 structure): H1 = gelu(Xb3 @ Wr3^T + rb1) ----
__global__ __launch_bounds__(256, 2) void router_gemm_kernel(
    const u16* __restrict__ A, const u16* __restrict__ Bm,
    const float* __restrict__ rb1, float* __restrict__ H1) {
  __shared__ __attribute__((aligned(16))) u16 lA[128 * 32];
  __shared__ __attribute__((aligned(16))) u16 lB[128 * 32];
  int tid = threadIdx.x;
  int gid = blockIdx.x;
  int cpx = gridDim.x >> 3;
  gid = (gid & 7) * cpx + (gid >> 3);
  int bandsz = 2 * 8;
  int band = gid / bandsz, inb = gid % bandsz;
  long m0 = (long)(band * 8 + (inb & 7)) * 128;
  long n0 = (long)(inb >> 3) * 128;
  int wid = tid >> 6, lane = tid & 63;
  int wm = wid >> 1, wn = wid & 1;
  f32x4 acc[4][4];
#pragma unroll
  for (int m = 0; m < 4; m++)
#pragma unroll
    for (int n = 0; n < 4; n++) acc[m][n] = (f32x4){0.f, 0.f, 0.f, 0.f};
  int lr = lane & 15, lk = (lane >> 4) * 8;
  int srow = tid >> 2, soff = (tid & 3) * 8;
  const u16* Ab = A + m0 * K3_;
  const u16* Bb = Bm + n0 * K3_;
  for (int k0 = 0; k0 < K3_; k0 += 32) {
    gload16(Ab + (long)srow * K3_ + k0 + soff, &lA[tid * 8]);
    gload16(Ab + (long)(64 + srow) * K3_ + k0 + soff, &lA[(256 + tid) * 8]);
    gload16(Bb + (long)srow * K3_ + k0 + soff, &lB[tid * 8]);
    gload16(Bb + (long)(64 + srow) * K3_ + k0 + soff, &lB[(256 + tid) * 8]);
    __syncthreads();
    bf16x8 af[4], bfr[4];
#pragma unroll
    for (int m = 0; m < 4; m++)
      af[m] = *reinterpret_cast<const bf16x8*>(&lA[(wm * 64 + m * 16 + lr) * 32 + lk]);
#pragma unroll
    for (int n = 0; n < 4; n++)
      bfr[n] = *reinterpret_cast<const bf16x8*>(&lB[(wn * 64 + n * 16 + lr) * 32 + lk]);
#pragma unroll
    for (int m = 0; m < 4; m++)
#pragma unroll
      for (int n = 0; n < 4; n++)
        acc[m][n] = __builtin_amdgcn_mfma_f32_16x16x32_bf16(af[m], bfr[n], acc[m][n], 0, 0, 0);
    __syncthreads();
  }
  int lq = lane >> 4;
#pragma unroll
  for (int m = 0; m < 4; m++)
#pragma unroll
    for (int n = 0; n < 4; n++)
#pragma unroll
      for (int j = 0; j < 4; j++) {
        long row = m0 + wm * 64 + m * 16 + lq * 4 + j;
        long col = n0 + wn * 64 + n * 16 + lr;
        if (col < RC_)
          H1[row * RC_ + col] = gelu_exact(acc[m][n][j] + rb1[col]);
      }
}

// -------- router layer 2 + softmax + path products + top-k + renorm --------
__global__ __launch_bounds__(256) void router_logits_kernel(
    const float* __restrict__ H1, const float* __restrict__ rW2,
    const float* __restrict__ rb2, const int* __restrict__ topk_ptr,
    float* __restrict__ P) {
  int b = blockIdx.x * 256 + threadIdx.x;
  const float* hrow = H1 + (long)b * RC_;
  float dec[NN_][2];
#pragma unroll
  for (int n = 0; n < NN_; n++) {
    float l0 = rb2[n * 2], l1 = rb2[n * 2 + 1];
#pragma unroll
    for (int r4 = 0; r4 < HR_; r4 += 4) {
      f32x4 h = *reinterpret_cast<const f32x4*>(hrow + n * HR_ + r4);
#pragma unroll
      for (int j = 0; j < 4; j++) {
        l0 += h[j] * rW2[(n * HR_ + r4 + j) * 2];
        l1 += h[j] * rW2[(n * HR_ + r4 + j) * 2 + 1];
      }
    }
    float mx = fmaxf(l0, l1);
    float e0 = expf(l0 - mx), e1 = expf(l1 - mx);
    float s = e0 + e1;
    dec[n][0] = e0 / s; dec[n][1] = e1 / s;
  }
  float v[NL_];
#pragma unroll
  for (int L = 0; L < NL_; L++)
    v[L] = dec[0][L >> 2] * dec[1 + (L >> 2)][(L >> 1) & 1] * dec[3 + (L >> 1)][L & 1];
  int tk = *topk_ptr;
  float p[NL_];
  if (tk < NL_) {
    float s = 0.f;
    bool keep[NL_];
#pragma unroll
    for (int e = 0; e < NL_; e++) {
      int rank = 0;
#pragma unroll
      for (int j = 0; j < NL_; j++)
        rank += ((v[j] > v[e]) || (v[j] == v[e] && j < e)) ? 1 : 0;
      keep[e] = rank < tk;
      if (keep[e]) s += v[e];
    }
    float inv = 1.f / (s + 1e-8f);
#pragma unroll
    for (int e = 0; e < NL_; e++) p[e] = keep[e] ? v[e] * inv : 0.f;
  } else {
#pragma unroll
    for (int e = 0; e < NL_; e++) p[e] = v[e];
  }
#pragma unroll
  for (int e = 0; e < NL_; e++) P[(long)b * NL_ + e] = p[e];
}

// ---- y init: y[b][o] = sum_e P[b][e]*eb2[e][o] ----------------------------
__global__ __launch_bounds__(256) void yinit_kernel(
    const float* __restrict__ P, const float* __restrict__ eb2,
    float* __restrict__ y) {
  size_t i = ((size_t)blockIdx.x * 256 + threadIdx.x) * 4;
  size_t row = i >> 10;
  int col = (int)(i & 1023);
  f32x4 s = (f32x4){0.f, 0.f, 0.f, 0.f};
#pragma unroll
  for (int e = 0; e < NL_; e++) {
    float pe = P[row * NL_ + e];
    f32x4 w = *reinterpret_cast<const f32x4*>(eb2 + (size_t)e * O_ + col);
    s += w * pe;
  }
  *reinterpret_cast<f32x4*>(y + i) = s;
}

// ---- deterministic per-expert row compaction (block scan, no atomics) -----
// block e: idx[e*B_ + j] = j-th row (ascending) with P[row][e] > 0; counts[e].
__global__ __launch_bounds__(256) void compact_kernel(
    const float* __restrict__ P, int* __restrict__ idx,
    int* __restrict__ counts) {
  int e = blockIdx.x, t = threadIdx.x;
  __shared__ int sc[256];
  __shared__ int sbase;
  if (t == 0) sbase = 0;
  __syncthreads();
  for (int c0 = 0; c0 < B_; c0 += 256) {
    int r = c0 + t;
    int f = (P[(long)r * NL_ + e] > 0.f) ? 1 : 0;
    sc[t] = f;
    __syncthreads();
#pragma unroll
    for (int d = 1; d < 256; d <<= 1) {
      int v = (t >= d) ? sc[t - d] : 0;
      __syncthreads();
      sc[t] += v;
      __syncthreads();
    }
    int pos = sbase + sc[t] - 1;
    int tot = sc[255];
    if (f) idx[(long)e * B_ + pos] = r;
    __syncthreads();
    if (t == 0) sbase += tot;
    __syncthreads();
  }
  if (t == 0) counts[e] = sbase;
}

// ======== sparse expert GEMM, m97 128x128 structure (proven ~900 TF) =======
// MODE 0: A-rows gathered via idx (Xb3 hi part, K=1024); out bf16
//         H[lrow][col] = bf16( gelu(acc + bias[col]) * P[idx[lrow]][expert] )
// MODE 1: A = compact H (dense rows, K=2048); out f32 scatter-accumulate
//         y[idx[lrow]][col] += acc
// Blocks with m0 >= counts[expert] exit immediately.
template<int MODE>
__global__ __launch_bounds__(256, 2) void gemms_kernel(
    const u16* __restrict__ A, const u16* __restrict__ Bm,
    const float* __restrict__ bias, const float* __restrict__ P,
    void* __restrict__ outp, const int* __restrict__ idxe,
    const int* __restrict__ counts, int expert,
    int lda, int ldb, int ldo, int tiles_n, int K) {
  __shared__ __attribute__((aligned(16))) u16 lA[128 * 32];
  __shared__ __attribute__((aligned(16))) u16 lB[128 * 32];
  int cnt = counts[expert];
  int tid = threadIdx.x;
  int gid = blockIdx.x;
  int cpx = gridDim.x >> 3;
  gid = (gid & 7) * cpx + (gid >> 3);      // bijective XCD swizzle (grid%8==0)
  int bandsz = tiles_n * 8;
  int band = gid / bandsz, inb = gid % bandsz;
  long m0 = (long)(band * 8 + (inb & 7)) * 128;
  long n0 = (long)(inb >> 3) * 128;
  if (m0 >= cnt) return;
  int wid = tid >> 6, lane = tid & 63;
  int wm = wid >> 1, wn = wid & 1;
  f32x4 acc[4][4];
#pragma unroll
  for (int m = 0; m < 4; m++)
#pragma unroll
    for (int n = 0; n < 4; n++) acc[m][n] = (f32x4){0.f, 0.f, 0.f, 0.f};
  int lr = lane & 15, lk = (lane >> 4) * 8;
  int srow = tid >> 2, soff = (tid & 3) * 8;
  const u16 *ar0, *ar1;
  if (MODE == 0) {
    int gi0 = (m0 + srow < cnt) ? idxe[m0 + srow] : 0;
    int gi1 = (m0 + 64 + srow < cnt) ? idxe[m0 + 64 + srow] : 0;
    ar0 = A + (long)gi0 * lda;
    ar1 = A + (long)gi1 * lda;
  } else {
    ar0 = A + (m0 + srow) * lda;            // rows >= cnt read garbage H:
    ar1 = A + (m0 + 64 + srow) * lda;       // finite bf16, outputs discarded
  }
  const u16* Bb = Bm + n0 * ldb;
  for (int k0 = 0; k0 < K; k0 += 32) {
    gload16(ar0 + k0 + soff, &lA[tid * 8]);
    gload16(ar1 + k0 + soff, &lA[(256 + tid) * 8]);
    gload16(Bb + (long)srow * ldb + k0 + soff, &lB[tid * 8]);
    gload16(Bb + (long)(64 + srow) * ldb + k0 + soff, &lB[(256 + tid) * 8]);
    __syncthreads();
    bf16x8 af[4], bfr[4];
#pragma unroll
    for (int m = 0; m < 4; m++)
      af[m] = *reinterpret_cast<const bf16x8*>(&lA[(wm * 64 + m * 16 + lr) * 32 + lk]);
#pragma unroll
    for (int n = 0; n < 4; n++)
      bfr[n] = *reinterpret_cast<const bf16x8*>(&lB[(wn * 64 + n * 16 + lr) * 32 + lk]);
#pragma unroll
    for (int m = 0; m < 4; m++)
#pragma unroll
      for (int n = 0; n < 4; n++)
        acc[m][n] = __builtin_amdgcn_mfma_f32_16x16x32_bf16(af[m], bfr[n], acc[m][n], 0, 0, 0);
    __syncthreads();
  }
  int lq = lane >> 4;
#pragma unroll
  for (int m = 0; m < 4; m++) {
#pragma unroll
    for (int j = 0; j < 4; j++) {
      long lrow = m0 + wm * 64 + m * 16 + lq * 4 + j;
      if (lrow >= cnt) continue;
      int orow = idxe[lrow];
      if (MODE == 0) {
        float pw = P[(long)orow * NL_ + expert];
#pragma unroll
        for (int n = 0; n < 4; n++) {
          long col = n0 + wn * 64 + n * 16 + lr;
          float g = gelu_exact(acc[m][n][j] + bias[col]);
          ((u16*)outp)[lrow * ldo + col] = f2bf(g * pw);
        }
      } else {
#pragma unroll
        for (int n = 0; n < 4; n++) {
          long col = n0 + wn * 64 + n * 16 + lr;
          ((float*)outp)[(long)orow * ldo + col] += acc[m][n][j];
        }
      }
    }
  }
}

extern "C" void kernel_launch(void* const* d_in, const int* in_sizes, int n_in,
                              void* d_out, int out_size, void* d_ws, size_t ws_size,
                              hipStream_t stream) {
  (void)in_sizes; (void)n_in; (void)out_size; (void)ws_size;
  const float* x   = (const float*)d_in[0];
  const float* rW1 = (const float*)d_in[1];
  const float* rb1 = (const float*)d_in[2];
  const float* rW2 = (const float*)d_in[3];
  const float* rb2 = (const float*)d_in[4];
  const float* eW1 = (const float*)d_in[5];
  const float* eb1 = (const float*)d_in[6];
  const float* eW2 = (const float*)d_in[7];
  const float* eb2 = (const float*)d_in[8];
  const int*  topk = (const int*)d_in[9];
  float* y = (float*)d_out;
  float* P = y + (size_t)B_ * O_;   // leaf_probs live in d_out tail

  char* ws = (char*)d_ws;
  u16*  Xb3 = (u16*)ws;                                   // 48 MiB
  u16*  W1t = (u16*)(ws + 50331648);                      // 32 MiB
  u16*  W2t = (u16*)(ws + 83886080);                      // 32 MiB
  char* hreg = ws + 117440512;
  u16*  Hbuf = (u16*)hreg;                                // 32 MiB (per expert)
  u16*  Wr3  = (u16*)hreg;                                // dead before Hbuf use
  float* H1  = (float*)(hreg + 1572864);                  // dead before Hbuf use
  int*  idx    = (int*)(ws + 150994944);                  // 8*8192 ints
  int*  counts = (int*)(ws + 151257088);                  // 8 ints

  build_xb3_kernel<<<(B_ * D_) / 1024, 256, 0, stream>>>(x, Xb3);
  build_wr3_kernel<<<(256 * K3_) / 1024, 256, 0, stream>>>(rW1, Wr3);
  // W1t[e*HE+n][k] = eW1[e][k][n]
  transpose_cvt_kernel<<<dim3(HE_ / 64, D_ / 64, NL_), 256, 0, stream>>>(
      eW1, W1t, D_, HE_, D_, (long)D_ * HE_, (long)HE_ * D_);
  // W2t[o][e*HE+h] = eW2[e][h][o]
  transpose_cvt_kernel<<<dim3(O_ / 64, HE_ / 64, NL_), 256, 0, stream>>>(
      eW2, W2t, HE_, O_, NL_ * HE_, (long)HE_ * O_, (long)HE_);
  router_gemm_kernel<<<128, 256, 0, stream>>>(Xb3, Wr3, rb1, H1);
  router_logits_kernel<<<B_ / 256, 256, 0, stream>>>(H1, rW2, rb2, topk, P);
  yinit_kernel<<<(B_ * O_) / 1024, 256, 0, stream>>>(P, eb2, y);
  compact_kernel<<<NL_, 256, 0, stream>>>(P, idx, counts);

  for (int e = 0; e < NL_; e++) {
    // GEMM1 (gathered): rows with p_e>0 of Xb3(hi) @ W1t_e^T -> compact Hbuf
    gemms_kernel<0><<<64 * 16, 256, 0, stream>>>(
        Xb3, W1t + (size_t)e * HE_ * D_, eb1 + (size_t)e * HE_, P, Hbuf,
        idx + (size_t)e * B_, counts, e, K3_, D_, HE_, 16, D_);
    // GEMM2 (scatter): Hbuf @ W2t_e^T accumulated into y rows idx_e
    gemms_kernel<1><<<64 * 8, 256, 0, stream>>>(
        Hbuf, W2t + (size_t)e * HE_, nullptr, nullptr, y,
        idx + (size_t)e * B_, counts, e, HE_, (size_t)NL_ * HE_, O_, 8, HE_);
  }
}

// Round 7
// 721.812 us; speedup vs baseline: 1.4989x; 1.4989x over previous
//
#include <hip/hip_runtime.h>
#include <hip/hip_bf16.h>
#include <cstdint>

// Problem dims (fixed by the reference)
#define B_   8192
#define D_   1024
#define O_   1024
#define HE_  2048
#define NN_  7     // decision nodes
#define NL_  8     // leaves / experts
#define HR_  32    // router hidden
#define RC_  224   // NN_*HR_
#define K3_  3072  // router split-GEMM K (hi|hi|lo)
#define MTMAX_ 264 // max total m-tiles over experts (topk=4: <=264)

typedef __attribute__((ext_vector_type(2))) float f32x2;
typedef __attribute__((ext_vector_type(4))) float f32x4;
typedef __attribute__((ext_vector_type(8))) short bf16x8;
typedef __attribute__((ext_vector_type(4))) unsigned short u16x4;
typedef unsigned short u16;
typedef unsigned int u32;

__device__ __forceinline__ u16 f2bf(float f) {
  __hip_bfloat16 h = __float2bfloat16(f);
  return *reinterpret_cast<u16*>(&h);
}
__device__ __forceinline__ float bf2f(u16 u) {
  u32 v = ((u32)u) << 16;
  return *reinterpret_cast<float*>(&v);
}
__device__ __forceinline__ float gelu_exact(float v) {
  return 0.5f * v * (1.0f + erff(v * 0.7071067811865475f));
}
__device__ __forceinline__ void gload16(const void* g, void* l) {
  __builtin_amdgcn_global_load_lds(
      (const __attribute__((address_space(1))) void*)(uintptr_t)g,
      (__attribute__((address_space(3))) void*)(uintptr_t)l,
      16, 0, 0);
}

// ---- Xbs[b][2048] = [bf16(x) | bf16(x - bf16(x))]  (hi | lo) --------------
__global__ __launch_bounds__(256) void build_xbs_kernel(
    const float* __restrict__ in, u16* __restrict__ out) {
  size_t i = ((size_t)blockIdx.x * 256 + threadIdx.x) * 4;
  size_t row = i >> 10;
  int col = (int)(i & 1023);
  f32x4 f = *reinterpret_cast<const f32x4*>(in + i);
  u16x4 hi, lo;
#pragma unroll
  for (int j = 0; j < 4; j++) {
    hi[j] = f2bf(f[j]);
    lo[j] = f2bf(f[j] - bf2f(hi[j]));
  }
  u16* base = out + row * 2048 + col;
  *reinterpret_cast<u16x4*>(base)        = hi;
  *reinterpret_cast<u16x4*>(base + 1024) = lo;
}

// ---- Wr3[256][3072]: rows c<224 = [w_hi | w_lo | w_hi] of rW1[n][k][h] ----
__global__ __launch_bounds__(256) void build_wr3_kernel(
    const float* __restrict__ rW1, u16* __restrict__ Wr3) {
  size_t i = ((size_t)blockIdx.x * 256 + threadIdx.x) * 4;  // over 256*3072
  int c = (int)(i / K3_), k = (int)(i % K3_);
  int j = k >> 10, kk = k & 1023;
  u16x4 o;
  if (c < RC_) {
    int node = c >> 5, h = c & 31;
    const float* src = rW1 + ((size_t)node * 1024 + kk) * HR_ + h;
#pragma unroll
    for (int t = 0; t < 4; t++) {
      float f = src[t * HR_];
      u16 hi = f2bf(f);
      o[t] = (j == 1) ? f2bf(f - bf2f(hi)) : hi;
    }
  } else {
    o[0] = 0; o[1] = 0; o[2] = 0; o[3] = 0;
  }
  *reinterpret_cast<u16x4*>(Wr3 + i) = o;
}

// ------------- transpose + cvt: out[c*ldo + r] (+e*out_estride) = in[r][c] --
__global__ __launch_bounds__(256) void transpose_cvt_kernel(
    const float* __restrict__ in, u16* __restrict__ out,
    int R, int C, int ldo, long in_estride, long out_estride) {
  __shared__ __attribute__((aligned(16))) float tile[64][65];
  const float* in_e = in + (long)blockIdx.z * in_estride;
  u16* out_e = out + (long)blockIdx.z * out_estride;
  int t = threadIdx.x;
  int r0 = blockIdx.y * 64, c0 = blockIdx.x * 64;
  int cc = t & 63, rbase = t >> 6;
#pragma unroll
  for (int i = 0; i < 16; i++) {
    int rr = rbase + i * 4;
    tile[rr][cc] = in_e[(long)(r0 + rr) * C + c0 + cc];
  }
  __syncthreads();
  int r2 = (t & 31) * 2, cj = t >> 5;
#pragma unroll
  for (int i = 0; i < 8; i++) {
    int c = cj * 8 + i;
    u32 u = (u32)f2bf(tile[r2][c]) | ((u32)f2bf(tile[r2 + 1][c]) << 16);
    *reinterpret_cast<u32*>(out_e + (long)(c0 + c) * ldo + r0 + r2) = u;
  }
}

// ---- router GEMM, split-K=4: H1p[s] = Xbs(mapped) @ Wr3^T  (raw, no gelu) -
// logical k: [0,1024)=hi, [1024,2048)=hi, [2048,3072)=lo; col=k0<1024?k0:k0-1024
__global__ __launch_bounds__(256, 2) void router_gemm_kernel(
    const u16* __restrict__ Xbs, const u16* __restrict__ Bm,
    float* __restrict__ H1p) {
  __shared__ __attribute__((aligned(16))) u16 lA[128 * 32];
  __shared__ __attribute__((aligned(16))) u16 lB[128 * 32];
  int tid = threadIdx.x;
  int gid = blockIdx.x;
  int cpx = gridDim.x >> 3;
  gid = (gid & 7) * cpx + (gid >> 3);
  int s = gid >> 7;                  // split id 0..3
  int rem = gid & 127;
  int band = rem >> 4, inb = rem & 15;
  long m0 = (long)(band * 8 + (inb & 7)) * 128;
  long n0 = (long)(inb >> 3) * 128;
  int wid = tid >> 6, lane = tid & 63;
  int wm = wid >> 1, wn = wid & 1;
  f32x4 acc[4][4];
#pragma unroll
  for (int m = 0; m < 4; m++)
#pragma unroll
    for (int n = 0; n < 4; n++) acc[m][n] = (f32x4){0.f, 0.f, 0.f, 0.f};
  int lr = lane & 15, lk = (lane >> 4) * 8;
  int srow = tid >> 2, soff = (tid & 3) * 8;
  const u16* Bb = Bm + n0 * K3_;
  int kbeg = s * 768, kend = kbeg + 768;
  for (int k0 = kbeg; k0 < kend; k0 += 32) {
    int ca = (k0 < 1024) ? k0 : k0 - 1024;   // hi / hi / lo remap
    gload16(Xbs + (m0 + srow) * 2048 + ca + soff, &lA[tid * 8]);
    gload16(Xbs + (m0 + 64 + srow) * 2048 + ca + soff, &lA[(256 + tid) * 8]);
    gload16(Bb + (long)srow * K3_ + k0 + soff, &lB[tid * 8]);
    gload16(Bb + (long)(64 + srow) * K3_ + k0 + soff, &lB[(256 + tid) * 8]);
    __syncthreads();
    bf16x8 af[4], bfr[4];
#pragma unroll
    for (int m = 0; m < 4; m++)
      af[m] = *reinterpret_cast<const bf16x8*>(&lA[(wm * 64 + m * 16 + lr) * 32 + lk]);
#pragma unroll
    for (int n = 0; n < 4; n++)
      bfr[n] = *reinterpret_cast<const bf16x8*>(&lB[(wn * 64 + n * 16 + lr) * 32 + lk]);
#pragma unroll
    for (int m = 0; m < 4; m++)
#pragma unroll
      for (int n = 0; n < 4; n++)
        acc[m][n] = __builtin_amdgcn_mfma_f32_16x16x32_bf16(af[m], bfr[n], acc[m][n], 0, 0, 0);
    __syncthreads();
  }
  int lq = lane >> 4;
#pragma unroll
  for (int m = 0; m < 4; m++)
#pragma unroll
    for (int n = 0; n < 4; n++)
#pragma unroll
      for (int j = 0; j < 4; j++) {
        long row = m0 + wm * 64 + m * 16 + lq * 4 + j;
        long col = n0 + wn * 64 + n * 16 + lr;
        if (col < RC_)
          H1p[((long)s * B_ + row) * RC_ + col] = acc[m][n][j];
      }
}

// -------- router layer 2: sum split-K partials + bias + gelu, softmax, -----
// -------- path products, top-k, renorm ------------------------------------
__global__ __launch_bounds__(256) void router_logits_kernel(
    const float* __restrict__ H1p, const float* __restrict__ rb1,
    const float* __restrict__ rW2, const float* __restrict__ rb2,
    const int* __restrict__ topk_ptr, float* __restrict__ P) {
  int b = blockIdx.x * 256 + threadIdx.x;
  float dec[NN_][2];
#pragma unroll
  for (int n = 0; n < NN_; n++) {
    float l0 = rb2[n * 2], l1 = rb2[n * 2 + 1];
#pragma unroll
    for (int r4 = 0; r4 < HR_; r4 += 4) {
      int c = n * HR_ + r4;
      f32x4 hs = *reinterpret_cast<const f32x4*>(&H1p[((long)0 * B_ + b) * RC_ + c]);
#pragma unroll
      for (int s = 1; s < 4; s++)
        hs += *reinterpret_cast<const f32x4*>(&H1p[((long)s * B_ + b) * RC_ + c]);
      f32x4 bv = *reinterpret_cast<const f32x4*>(rb1 + c);
#pragma unroll
      for (int j = 0; j < 4; j++) {
        float hv = gelu_exact(hs[j] + bv[j]);
        l0 += hv * rW2[(c + j) * 2];
        l1 += hv * rW2[(c + j) * 2 + 1];
      }
    }
    float mx = fmaxf(l0, l1);
    float e0 = expf(l0 - mx), e1 = expf(l1 - mx);
    float sm = e0 + e1;
    dec[n][0] = e0 / sm; dec[n][1] = e1 / sm;
  }
  float v[NL_];
#pragma unroll
  for (int L = 0; L < NL_; L++)
    v[L] = dec[0][L >> 2] * dec[1 + (L >> 2)][(L >> 1) & 1] * dec[3 + (L >> 1)][L & 1];
  int tk = *topk_ptr;
  float p[NL_];
  if (tk < NL_) {
    float s = 0.f;
    bool keep[NL_];
#pragma unroll
    for (int e = 0; e < NL_; e++) {
      int rank = 0;
#pragma unroll
      for (int j = 0; j < NL_; j++)
        rank += ((v[j] > v[e]) || (v[j] == v[e] && j < e)) ? 1 : 0;
      keep[e] = rank < tk;
      if (keep[e]) s += v[e];
    }
    float inv = 1.f / (s + 1e-8f);
#pragma unroll
    for (int e = 0; e < NL_; e++) p[e] = keep[e] ? v[e] * inv : 0.f;
  } else {
#pragma unroll
    for (int e = 0; e < NL_; e++) p[e] = v[e];
  }
#pragma unroll
  for (int e = 0; e < NL_; e++) P[(long)b * NL_ + e] = p[e];
}

// ---- y init: y[b][o] = sum_e P[b][e]*eb2[e][o] ----------------------------
__global__ __launch_bounds__(256) void yinit_kernel(
    const float* __restrict__ P, const float* __restrict__ eb2,
    float* __restrict__ y) {
  size_t i = ((size_t)blockIdx.x * 256 + threadIdx.x) * 4;
  size_t row = i >> 10;
  int col = (int)(i & 1023);
  f32x4 s = (f32x4){0.f, 0.f, 0.f, 0.f};
#pragma unroll
  for (int e = 0; e < NL_; e++) {
    float pe = P[row * NL_ + e];
    f32x4 w = *reinterpret_cast<const f32x4*>(eb2 + (size_t)e * O_ + col);
    s += w * pe;
  }
  *reinterpret_cast<f32x4*>(y + i) = s;
}

// ---- deterministic per-expert row compaction (block scan, no atomics) -----
__global__ __launch_bounds__(256) void compact_kernel(
    const float* __restrict__ P, int* __restrict__ idx,
    int* __restrict__ counts) {
  int e = blockIdx.x, t = threadIdx.x;
  __shared__ int sc[256];
  __shared__ int sbase;
  if (t == 0) sbase = 0;
  __syncthreads();
  for (int c0 = 0; c0 < B_; c0 += 256) {
    int r = c0 + t;
    int f = (P[(long)r * NL_ + e] > 0.f) ? 1 : 0;
    sc[t] = f;
    __syncthreads();
#pragma unroll
    for (int d = 1; d < 256; d <<= 1) {
      int v = (t >= d) ? sc[t - d] : 0;
      __syncthreads();
      sc[t] += v;
      __syncthreads();
    }
    int pos = sbase + sc[t] - 1;
    int tot = sc[255];
    if (f) idx[(long)e * B_ + pos] = r;
    __syncthreads();
    if (t == 0) sbase += tot;
    __syncthreads();
  }
  if (t == 0) counts[e] = sbase;
}

// ---- tile-offset prefix: toff[e] = sum_{f<e} ceil(cnt_f/128), toff[8]=tot -
__global__ void tiles_kernel(const int* __restrict__ counts,
                             int* __restrict__ toff) {
  int s = 0;
#pragma unroll
  for (int e = 0; e < NL_; e++) { toff[e] = s; s += (counts[e] + 127) >> 7; }
  toff[NL_] = s;
}

// ======== grouped sparse expert GEMM1 (all experts, one dispatch) ==========
// block -> (expert e via toff, m-tile, n-tile). A rows gathered via idx_e
// from Xbs hi (K=1024). Out: Hall[(toff[e]*128+lrow)*2048+col] =
//   bf16( gelu(acc + eb1[e*2048+col]) * P[orow][e] ).  m97 128x128 body.
__global__ __launch_bounds__(256, 2) void gemme1_kernel(
    const u16* __restrict__ Xbs, const u16* __restrict__ W1t,
    const float* __restrict__ eb1, const float* __restrict__ P,
    u16* __restrict__ Hall, const int* __restrict__ idx,
    const int* __restrict__ counts, const int* __restrict__ toff) {
  __shared__ __attribute__((aligned(16))) u16 lA[128 * 32];
  __shared__ __attribute__((aligned(16))) u16 lB[128 * 32];
  int tid = threadIdx.x;
  int gid = blockIdx.x;
  int cpx = gridDim.x >> 3;
  gid = (gid & 7) * cpx + (gid >> 3);      // XCD swizzle (grid%8==0)
  int mt = gid >> 4, nt = gid & 15;
  if (mt >= toff[NL_]) return;
  int e = 0;
#pragma unroll
  for (int f = 1; f < NL_; f++) e += (mt >= toff[f]) ? 1 : 0;
  int cnt = counts[e];
  long m0 = (long)(mt - toff[e]) * 128;
  long n0 = (long)nt * 128;
  const int* idxe = idx + (long)e * B_;
  int wid = tid >> 6, lane = tid & 63;
  int wm = wid >> 1, wn = wid & 1;
  f32x4 acc[4][4];
#pragma unroll
  for (int m = 0; m < 4; m++)
#pragma unroll
    for (int n = 0; n < 4; n++) acc[m][n] = (f32x4){0.f, 0.f, 0.f, 0.f};
  int lr = lane & 15, lk = (lane >> 4) * 8;
  int srow = tid >> 2, soff = (tid & 3) * 8;
  int gi0 = (m0 + srow < cnt) ? idxe[m0 + srow] : 0;
  int gi1 = (m0 + 64 + srow < cnt) ? idxe[m0 + 64 + srow] : 0;
  const u16* ar0 = Xbs + (long)gi0 * 2048;
  const u16* ar1 = Xbs + (long)gi1 * 2048;
  const u16* Bb = W1t + ((size_t)e * HE_ + n0) * D_;
  for (int k0 = 0; k0 < D_; k0 += 32) {
    gload16(ar0 + k0 + soff, &lA[tid * 8]);
    gload16(ar1 + k0 + soff, &lA[(256 + tid) * 8]);
    gload16(Bb + (long)srow * D_ + k0 + soff, &lB[tid * 8]);
    gload16(Bb + (long)(64 + srow) * D_ + k0 + soff, &lB[(256 + tid) * 8]);
    __syncthreads();
    bf16x8 af[4], bfr[4];
#pragma unroll
    for (int m = 0; m < 4; m++)
      af[m] = *reinterpret_cast<const bf16x8*>(&lA[(wm * 64 + m * 16 + lr) * 32 + lk]);
#pragma unroll
    for (int n = 0; n < 4; n++)
      bfr[n] = *reinterpret_cast<const bf16x8*>(&lB[(wn * 64 + n * 16 + lr) * 32 + lk]);
#pragma unroll
    for (int m = 0; m < 4; m++)
#pragma unroll
      for (int n = 0; n < 4; n++)
        acc[m][n] = __builtin_amdgcn_mfma_f32_16x16x32_bf16(af[m], bfr[n], acc[m][n], 0, 0, 0);
    __syncthreads();
  }
  int lq = lane >> 4;
  long hbase = (long)toff[e] * 128;
#pragma unroll
  for (int m = 0; m < 4; m++) {
#pragma unroll
    for (int j = 0; j < 4; j++) {
      long lrow = m0 + wm * 64 + m * 16 + lq * 4 + j;
      if (lrow >= cnt) continue;
      int orow = idxe[lrow];
      float pw = P[(long)orow * NL_ + e];
#pragma unroll
      for (int n = 0; n < 4; n++) {
        long col = n0 + wn * 64 + n * 16 + lr;
        float g = gelu_exact(acc[m][n][j] + eb1[(size_t)e * HE_ + col]);
        Hall[(hbase + lrow) * HE_ + col] = f2bf(g * pw);
      }
    }
  }
}

// ======== grouped sparse expert GEMM2 (all experts, one dispatch) ==========
// A = Hall compact rows (K=2048), B = W2t[o][e*2048+k] (ldb=16384).
// Scatter: y[orow][col] += acc via HW f32 atomic (low contention: 4/elt).
__global__ __launch_bounds__(256, 2) void gemme2_kernel(
    const u16* __restrict__ Hall, const u16* __restrict__ W2t,
    float* __restrict__ y, const int* __restrict__ idx,
    const int* __restrict__ counts, const int* __restrict__ toff) {
  __shared__ __attribute__((aligned(16))) u16 lA[128 * 32];
  __shared__ __attribute__((aligned(16))) u16 lB[128 * 32];
  int tid = threadIdx.x;
  int gid = blockIdx.x;
  int cpx = gridDim.x >> 3;
  gid = (gid & 7) * cpx + (gid >> 3);
  int mt = gid >> 3, nt = gid & 7;
  if (mt >= toff[NL_]) return;
  int e = 0;
#pragma unroll
  for (int f = 1; f < NL_; f++) e += (mt >= toff[f]) ? 1 : 0;
  int cnt = counts[e];
  long m0 = (long)(mt - toff[e]) * 128;
  long n0 = (long)nt * 128;
  const int* idxe = idx + (long)e * B_;
  int wid = tid >> 6, lane = tid & 63;
  int wm = wid >> 1, wn = wid & 1;
  f32x4 acc[4][4];
#pragma unroll
  for (int m = 0; m < 4; m++)
#pragma unroll
    for (int n = 0; n < 4; n++) acc[m][n] = (f32x4){0.f, 0.f, 0.f, 0.f};
  int lr = lane & 15, lk = (lane >> 4) * 8;
  int srow = tid >> 2, soff = (tid & 3) * 8;
  const u16* Ab = Hall + ((long)toff[e] * 128 + m0) * HE_;
  const u16* Bb = W2t + n0 * ((size_t)NL_ * HE_) + (size_t)e * HE_;
  for (int k0 = 0; k0 < HE_; k0 += 32) {
    gload16(Ab + (long)srow * HE_ + k0 + soff, &lA[tid * 8]);
    gload16(Ab + (long)(64 + srow) * HE_ + k0 + soff, &lA[(256 + tid) * 8]);
    gload16(Bb + (size_t)srow * (NL_ * HE_) + k0 + soff, &lB[tid * 8]);
    gload16(Bb + (size_t)(64 + srow) * (NL_ * HE_) + k0 + soff, &lB[(256 + tid) * 8]);
    __syncthreads();
    bf16x8 af[4], bfr[4];
#pragma unroll
    for (int m = 0; m < 4; m++)
      af[m] = *reinterpret_cast<const bf16x8*>(&lA[(wm * 64 + m * 16 + lr) * 32 + lk]);
#pragma unroll
    for (int n = 0; n < 4; n++)
      bfr[n] = *reinterpret_cast<const bf16x8*>(&lB[(wn * 64 + n * 16 + lr) * 32 + lk]);
#pragma unroll
    for (int m = 0; m < 4; m++)
#pragma unroll
      for (int n = 0; n < 4; n++)
        acc[m][n] = __builtin_amdgcn_mfma_f32_16x16x32_bf16(af[m], bfr[n], acc[m][n], 0, 0, 0);
    __syncthreads();
  }
  int lq = lane >> 4;
#pragma unroll
  for (int m = 0; m < 4; m++) {
#pragma unroll
    for (int j = 0; j < 4; j++) {
      long lrow = m0 + wm * 64 + m * 16 + lq * 4 + j;
      if (lrow >= cnt) continue;
      long orow = idxe[lrow];
#pragma unroll
      for (int n = 0; n < 4; n++) {
        long col = n0 + wn * 64 + n * 16 + lr;
        unsafeAtomicAdd(&y[orow * O_ + col], acc[m][n][j]);
      }
    }
  }
}

extern "C" void kernel_launch(void* const* d_in, const int* in_sizes, int n_in,
                              void* d_out, int out_size, void* d_ws, size_t ws_size,
                              hipStream_t stream) {
  (void)in_sizes; (void)n_in; (void)out_size; (void)ws_size;
  const float* x   = (const float*)d_in[0];
  const float* rW1 = (const float*)d_in[1];
  const float* rb1 = (const float*)d_in[2];
  const float* rW2 = (const float*)d_in[3];
  const float* rb2 = (const float*)d_in[4];
  const float* eW1 = (const float*)d_in[5];
  const float* eb1 = (const float*)d_in[6];
  const float* eW2 = (const float*)d_in[7];
  const float* eb2 = (const float*)d_in[8];
  const int*  topk = (const int*)d_in[9];
  float* y = (float*)d_out;
  float* P = y + (size_t)B_ * O_;   // leaf_probs live in d_out tail

  // ws layout (high-water 228.3 MiB, fits proven >=240 MiB):
  char* ws = (char*)d_ws;
  u16*  Xbs = (u16*)ws;                                   // 32 MiB [hi|lo]
  u16*  W1t = (u16*)(ws + 33554432);                      // 32 MiB
  u16*  W2t = (u16*)(ws + 67108864);                      // 32 MiB
  int*  idx    = (int*)(ws + 100663296);                  // 256 KiB
  int*  counts = (int*)(ws + 100925440);                  // 32 B
  int*  toff   = (int*)(ws + 100925504);                  // 36 B
  char* hreg   = ws + 100925952;                          // Hall region
  u16*  Hall = (u16*)hreg;                                // 33792x2048 bf16
  u16*  Wr3  = (u16*)hreg;                                // dead before Hall
  float* H1p = (float*)(hreg + 2097152);                  // dead before Hall

  build_xbs_kernel<<<(B_ * D_) / 1024, 256, 0, stream>>>(x, Xbs);
  build_wr3_kernel<<<(256 * K3_) / 1024, 256, 0, stream>>>(rW1, Wr3);
  // W1t[e*HE+n][k] = eW1[e][k][n]
  transpose_cvt_kernel<<<dim3(HE_ / 64, D_ / 64, NL_), 256, 0, stream>>>(
      eW1, W1t, D_, HE_, D_, (long)D_ * HE_, (long)HE_ * D_);
  // W2t[o][e*HE+h] = eW2[e][h][o]
  transpose_cvt_kernel<<<dim3(O_ / 64, HE_ / 64, NL_), 256, 0, stream>>>(
      eW2, W2t, HE_, O_, NL_ * HE_, (long)HE_ * O_, (long)HE_);
  router_gemm_kernel<<<512, 256, 0, stream>>>(Xbs, Wr3, H1p);
  router_logits_kernel<<<B_ / 256, 256, 0, stream>>>(H1p, rb1, rW2, rb2, topk, P);
  yinit_kernel<<<(B_ * O_) / 1024, 256, 0, stream>>>(P, eb2, y);
  compact_kernel<<<NL_, 256, 0, stream>>>(P, idx, counts);
  tiles_kernel<<<1, 1, 0, stream>>>(counts, toff);

  // grouped sparse expert GEMMs (one dispatch each, full GPU)
  gemme1_kernel<<<MTMAX_ * 16, 256, 0, stream>>>(
      Xbs, W1t, eb1, P, Hall, idx, counts, toff);
  gemme2_kernel<<<MTMAX_ * 8, 256, 0, stream>>>(
      Hall, W2t, y, idx, counts, toff);
}

// Round 8
// 669.637 us; speedup vs baseline: 1.6157x; 1.0779x over previous
//
#include <hip/hip_runtime.h>
#include <hip/hip_bf16.h>
#include <cstdint>

// Problem dims (fixed by the reference)
#define B_   8192
#define D_   1024
#define O_   1024
#define HE_  2048
#define NN_  7     // decision nodes
#define NL_  8     // leaves / experts
#define HR_  32    // router hidden
#define RC_  224   // NN_*HR_
#define K3_  3072  // router split-GEMM K (hi|hi|lo)
#define MTMAX_ 264 // max total m-tiles over experts (topk=4: <=264)

typedef __attribute__((ext_vector_type(2))) float f32x2;
typedef __attribute__((ext_vector_type(4))) float f32x4;
typedef __attribute__((ext_vector_type(8))) short bf16x8;
typedef __attribute__((ext_vector_type(4))) unsigned short u16x4;
typedef unsigned short u16;
typedef unsigned int u32;

__device__ __forceinline__ u16 f2bf(float f) {
  __hip_bfloat16 h = __float2bfloat16(f);
  return *reinterpret_cast<u16*>(&h);
}
__device__ __forceinline__ float bf2f(u16 u) {
  u32 v = ((u32)u) << 16;
  return *reinterpret_cast<float*>(&v);
}
__device__ __forceinline__ float gelu_exact(float v) {
  return 0.5f * v * (1.0f + erff(v * 0.7071067811865475f));
}
__device__ __forceinline__ void gload16(const void* g, void* l) {
  __builtin_amdgcn_global_load_lds(
      (const __attribute__((address_space(1))) void*)(uintptr_t)g,
      (__attribute__((address_space(3))) void*)(uintptr_t)l,
      16, 0, 0);
}

// ---- Xbs[b][2048] = [bf16(x) | bf16(x - bf16(x))]  (hi | lo) --------------
__global__ __launch_bounds__(256) void build_xbs_kernel(
    const float* __restrict__ in, u16* __restrict__ out) {
  size_t i = ((size_t)blockIdx.x * 256 + threadIdx.x) * 4;
  size_t row = i >> 10;
  int col = (int)(i & 1023);
  f32x4 f = *reinterpret_cast<const f32x4*>(in + i);
  u16x4 hi, lo;
#pragma unroll
  for (int j = 0; j < 4; j++) {
    hi[j] = f2bf(f[j]);
    lo[j] = f2bf(f[j] - bf2f(hi[j]));
  }
  u16* base = out + row * 2048 + col;
  *reinterpret_cast<u16x4*>(base)        = hi;
  *reinterpret_cast<u16x4*>(base + 1024) = lo;
}

// ---- Wr3[256][3072]: rows c<224 = [w_hi | w_lo | w_hi] of rW1[n][k][h] ----
__global__ __launch_bounds__(256) void build_wr3_kernel(
    const float* __restrict__ rW1, u16* __restrict__ Wr3) {
  size_t i = ((size_t)blockIdx.x * 256 + threadIdx.x) * 4;  // over 256*3072
  int c = (int)(i / K3_), k = (int)(i % K3_);
  int j = k >> 10, kk = k & 1023;
  u16x4 o;
  if (c < RC_) {
    int node = c >> 5, h = c & 31;
    const float* src = rW1 + ((size_t)node * 1024 + kk) * HR_ + h;
#pragma unroll
    for (int t = 0; t < 4; t++) {
      float f = src[t * HR_];
      u16 hi = f2bf(f);
      o[t] = (j == 1) ? f2bf(f - bf2f(hi)) : hi;
    }
  } else {
    o[0] = 0; o[1] = 0; o[2] = 0; o[3] = 0;
  }
  *reinterpret_cast<u16x4*>(Wr3 + i) = o;
}

// ------------- transpose + cvt: out[c*ldo + r] (+e*out_estride) = in[r][c] --
__global__ __launch_bounds__(256) void transpose_cvt_kernel(
    const float* __restrict__ in, u16* __restrict__ out,
    int R, int C, int ldo, long in_estride, long out_estride) {
  __shared__ __attribute__((aligned(16))) float tile[64][65];
  const float* in_e = in + (long)blockIdx.z * in_estride;
  u16* out_e = out + (long)blockIdx.z * out_estride;
  int t = threadIdx.x;
  int r0 = blockIdx.y * 64, c0 = blockIdx.x * 64;
  int cc = t & 63, rbase = t >> 6;
#pragma unroll
  for (int i = 0; i < 16; i++) {
    int rr = rbase + i * 4;
    tile[rr][cc] = in_e[(long)(r0 + rr) * C + c0 + cc];
  }
  __syncthreads();
  int r2 = (t & 31) * 2, cj = t >> 5;
#pragma unroll
  for (int i = 0; i < 8; i++) {
    int c = cj * 8 + i;
    u32 u = (u32)f2bf(tile[r2][c]) | ((u32)f2bf(tile[r2 + 1][c]) << 16);
    *reinterpret_cast<u32*>(out_e + (long)(c0 + c) * ldo + r0 + r2) = u;
  }
}

// ---- router GEMM, split-K=4: H1p[s] = Xbs(mapped) @ Wr3^T  (raw, no gelu) -
__global__ __launch_bounds__(256, 2) void router_gemm_kernel(
    const u16* __restrict__ Xbs, const u16* __restrict__ Bm,
    float* __restrict__ H1p) {
  __shared__ __attribute__((aligned(16))) u16 lA[128 * 32];
  __shared__ __attribute__((aligned(16))) u16 lB[128 * 32];
  int tid = threadIdx.x;
  int gid = blockIdx.x;
  int cpx = gridDim.x >> 3;
  gid = (gid & 7) * cpx + (gid >> 3);
  int s = gid >> 7;                  // split id 0..3
  int rem = gid & 127;
  int band = rem >> 4, inb = rem & 15;
  long m0 = (long)(band * 8 + (inb & 7)) * 128;
  long n0 = (long)(inb >> 3) * 128;
  int wid = tid >> 6, lane = tid & 63;
  int wm = wid >> 1, wn = wid & 1;
  f32x4 acc[4][4];
#pragma unroll
  for (int m = 0; m < 4; m++)
#pragma unroll
    for (int n = 0; n < 4; n++) acc[m][n] = (f32x4){0.f, 0.f, 0.f, 0.f};
  int lr = lane & 15, lk = (lane >> 4) * 8;
  int srow = tid >> 2, soff = (tid & 3) * 8;
  const u16* Bb = Bm + n0 * K3_;
  int kbeg = s * 768, kend = kbeg + 768;
  for (int k0 = kbeg; k0 < kend; k0 += 32) {
    int ca = (k0 < 1024) ? k0 : k0 - 1024;   // hi / hi / lo remap
    gload16(Xbs + (m0 + srow) * 2048 + ca + soff, &lA[tid * 8]);
    gload16(Xbs + (m0 + 64 + srow) * 2048 + ca + soff, &lA[(256 + tid) * 8]);
    gload16(Bb + (long)srow * K3_ + k0 + soff, &lB[tid * 8]);
    gload16(Bb + (long)(64 + srow) * K3_ + k0 + soff, &lB[(256 + tid) * 8]);
    __syncthreads();
    bf16x8 af[4], bfr[4];
#pragma unroll
    for (int m = 0; m < 4; m++)
      af[m] = *reinterpret_cast<const bf16x8*>(&lA[(wm * 64 + m * 16 + lr) * 32 + lk]);
#pragma unroll
    for (int n = 0; n < 4; n++)
      bfr[n] = *reinterpret_cast<const bf16x8*>(&lB[(wn * 64 + n * 16 + lr) * 32 + lk]);
#pragma unroll
    for (int m = 0; m < 4; m++)
#pragma unroll
      for (int n = 0; n < 4; n++)
        acc[m][n] = __builtin_amdgcn_mfma_f32_16x16x32_bf16(af[m], bfr[n], acc[m][n], 0, 0, 0);
    __syncthreads();
  }
  int lq = lane >> 4;
#pragma unroll
  for (int m = 0; m < 4; m++)
#pragma unroll
    for (int n = 0; n < 4; n++)
#pragma unroll
      for (int j = 0; j < 4; j++) {
        long row = m0 + wm * 64 + m * 16 + lq * 4 + j;
        long col = n0 + wn * 64 + n * 16 + lr;
        if (col < RC_)
          H1p[((long)s * B_ + row) * RC_ + col] = acc[m][n][j];
      }
}

// -------- router layer 2: sum split-K partials + bias + gelu, softmax, -----
__global__ __launch_bounds__(256) void router_logits_kernel(
    const float* __restrict__ H1p, const float* __restrict__ rb1,
    const float* __restrict__ rW2, const float* __restrict__ rb2,
    const int* __restrict__ topk_ptr, float* __restrict__ P) {
  int b = blockIdx.x * 256 + threadIdx.x;
  float dec[NN_][2];
#pragma unroll
  for (int n = 0; n < NN_; n++) {
    float l0 = rb2[n * 2], l1 = rb2[n * 2 + 1];
#pragma unroll
    for (int r4 = 0; r4 < HR_; r4 += 4) {
      int c = n * HR_ + r4;
      f32x4 hs = *reinterpret_cast<const f32x4*>(&H1p[((long)0 * B_ + b) * RC_ + c]);
#pragma unroll
      for (int s = 1; s < 4; s++)
        hs += *reinterpret_cast<const f32x4*>(&H1p[((long)s * B_ + b) * RC_ + c]);
      f32x4 bv = *reinterpret_cast<const f32x4*>(rb1 + c);
#pragma unroll
      for (int j = 0; j < 4; j++) {
        float hv = gelu_exact(hs[j] + bv[j]);
        l0 += hv * rW2[(c + j) * 2];
        l1 += hv * rW2[(c + j) * 2 + 1];
      }
    }
    float mx = fmaxf(l0, l1);
    float e0 = expf(l0 - mx), e1 = expf(l1 - mx);
    float sm = e0 + e1;
    dec[n][0] = e0 / sm; dec[n][1] = e1 / sm;
  }
  float v[NL_];
#pragma unroll
  for (int L = 0; L < NL_; L++)
    v[L] = dec[0][L >> 2] * dec[1 + (L >> 2)][(L >> 1) & 1] * dec[3 + (L >> 1)][L & 1];
  int tk = *topk_ptr;
  float p[NL_];
  if (tk < NL_) {
    float s = 0.f;
    bool keep[NL_];
#pragma unroll
    for (int e = 0; e < NL_; e++) {
      int rank = 0;
#pragma unroll
      for (int j = 0; j < NL_; j++)
        rank += ((v[j] > v[e]) || (v[j] == v[e] && j < e)) ? 1 : 0;
      keep[e] = rank < tk;
      if (keep[e]) s += v[e];
    }
    float inv = 1.f / (s + 1e-8f);
#pragma unroll
    for (int e = 0; e < NL_; e++) p[e] = keep[e] ? v[e] * inv : 0.f;
  } else {
#pragma unroll
    for (int e = 0; e < NL_; e++) p[e] = v[e];
  }
#pragma unroll
  for (int e = 0; e < NL_; e++) P[(long)b * NL_ + e] = p[e];
}

// ---- y init: y[b][o] = sum_e P[b][e]*eb2[e][o] ----------------------------
__global__ __launch_bounds__(256) void yinit_kernel(
    const float* __restrict__ P, const float* __restrict__ eb2,
    float* __restrict__ y) {
  size_t i = ((size_t)blockIdx.x * 256 + threadIdx.x) * 4;
  size_t row = i >> 10;
  int col = (int)(i & 1023);
  f32x4 s = (f32x4){0.f, 0.f, 0.f, 0.f};
#pragma unroll
  for (int e = 0; e < NL_; e++) {
    float pe = P[row * NL_ + e];
    f32x4 w = *reinterpret_cast<const f32x4*>(eb2 + (size_t)e * O_ + col);
    s += w * pe;
  }
  *reinterpret_cast<f32x4*>(y + i) = s;
}

// ---- deterministic per-expert row compaction (block scan, no atomics) -----
__global__ __launch_bounds__(256) void compact_kernel(
    const float* __restrict__ P, int* __restrict__ idx,
    int* __restrict__ counts) {
  int e = blockIdx.x, t = threadIdx.x;
  __shared__ int sc[256];
  __shared__ int sbase;
  if (t == 0) sbase = 0;
  __syncthreads();
  for (int c0 = 0; c0 < B_; c0 += 256) {
    int r = c0 + t;
    int f = (P[(long)r * NL_ + e] > 0.f) ? 1 : 0;
    sc[t] = f;
    __syncthreads();
#pragma unroll
    for (int d = 1; d < 256; d <<= 1) {
      int v = (t >= d) ? sc[t - d] : 0;
      __syncthreads();
      sc[t] += v;
      __syncthreads();
    }
    int pos = sbase + sc[t] - 1;
    int tot = sc[255];
    if (f) idx[(long)e * B_ + pos] = r;
    __syncthreads();
    if (t == 0) sbase += tot;
    __syncthreads();
  }
  if (t == 0) counts[e] = sbase;
}

// ---- tile-offset prefix: toff[e] = sum_{f<e} ceil(cnt_f/128), toff[8]=tot -
__global__ void tiles_kernel(const int* __restrict__ counts,
                             int* __restrict__ toff) {
  int s = 0;
#pragma unroll
  for (int e = 0; e < NL_; e++) { toff[e] = s; s += (counts[e] + 127) >> 7; }
  toff[NL_] = s;
}

// ======== grouped sparse expert GEMM1, BK=64 + XOR chunk swizzle ===========
// 128x128 tile, 4 waves 2x2, single-buffered 32KB LDS, 2 barriers / 64-K.
// LDS pos p (16B chunks, 8/row) of row r holds global chunk p^(r&7)
// (involution: staged from pre-swizzled source col, read at c^(r&7)).
__global__ __launch_bounds__(256, 2) void gemme1_kernel(
    const u16* __restrict__ Xbs, const u16* __restrict__ W1t,
    const float* __restrict__ eb1, const float* __restrict__ P,
    u16* __restrict__ Hall, const int* __restrict__ idx,
    const int* __restrict__ counts, const int* __restrict__ toff) {
  __shared__ __attribute__((aligned(16))) u16 lA[128 * 64];
  __shared__ __attribute__((aligned(16))) u16 lB[128 * 64];
  int tid = threadIdx.x;
  int gid = blockIdx.x;
  int cpx = gridDim.x >> 3;
  gid = (gid & 7) * cpx + (gid >> 3);      // XCD swizzle (grid%8==0)
  int mt = gid >> 4, nt = gid & 15;
  if (mt >= toff[NL_]) return;
  int e = 0;
#pragma unroll
  for (int f = 1; f < NL_; f++) e += (mt >= toff[f]) ? 1 : 0;
  int cnt = counts[e];
  long m0 = (long)(mt - toff[e]) * 128;
  long n0 = (long)nt * 128;
  const int* idxe = idx + (long)e * B_;
  int wid = tid >> 6, lane = tid & 63;
  int wm = wid >> 1, wn = wid & 1;
  f32x4 acc[4][4];
#pragma unroll
  for (int m = 0; m < 4; m++)
#pragma unroll
    for (int n = 0; n < 4; n++) acc[m][n] = (f32x4){0.f, 0.f, 0.f, 0.f};
  int lr = lane & 15, lkg = lane >> 4;
  // staging addresses: idx covers 128 rows x 8 chunks; 4 rounds of 256 thr
  const u16* gA[4]; const u16* gB[4]; int lds_o[4];
  const u16* Bb = W1t + ((size_t)e * HE_ + n0) * D_;
#pragma unroll
  for (int i = 0; i < 4; i++) {
    int sidx = tid + i * 256;
    int r = sidx >> 3, j = sidx & 7;
    int so = ((j ^ (r & 7)) << 3);           // pre-swizzled source col (elems)
    int gi = (m0 + r < cnt) ? idxe[m0 + r] : 0;
    gA[i] = Xbs + (long)gi * 2048 + so;
    gB[i] = Bb + (long)r * D_ + so;
    lds_o[i] = sidx * 8;
  }
  // read-side fragment byte offsets: row r chunk c at pos c^(r&7)
  int foA[4][2], foB[4][2];
#pragma unroll
  for (int m = 0; m < 4; m++) {
    int r = wm * 64 + m * 16 + lr;
#pragma unroll
    for (int kk = 0; kk < 2; kk++)
      foA[m][kk] = r * 128 + ((((kk * 4 + lkg) ^ (r & 7))) << 4);
  }
#pragma unroll
  for (int n = 0; n < 4; n++) {
    int r = wn * 64 + n * 16 + lr;
#pragma unroll
    for (int kk = 0; kk < 2; kk++)
      foB[n][kk] = r * 128 + ((((kk * 4 + lkg) ^ (r & 7))) << 4);
  }
  const char* pa = (const char*)lA;
  const char* pb = (const char*)lB;
  for (int k0 = 0; k0 < D_; k0 += 64) {
#pragma unroll
    for (int i = 0; i < 4; i++) gload16(gA[i] + k0, &lA[lds_o[i]]);
#pragma unroll
    for (int i = 0; i < 4; i++) gload16(gB[i] + k0, &lB[lds_o[i]]);
    __syncthreads();
    bf16x8 af[4][2], bfr[4][2];
#pragma unroll
    for (int m = 0; m < 4; m++) {
      af[m][0] = *reinterpret_cast<const bf16x8*>(pa + foA[m][0]);
      af[m][1] = *reinterpret_cast<const bf16x8*>(pa + foA[m][1]);
    }
#pragma unroll
    for (int n = 0; n < 4; n++) {
      bfr[n][0] = *reinterpret_cast<const bf16x8*>(pb + foB[n][0]);
      bfr[n][1] = *reinterpret_cast<const bf16x8*>(pb + foB[n][1]);
    }
#pragma unroll
    for (int m = 0; m < 4; m++)
#pragma unroll
      for (int n = 0; n < 4; n++) {
        acc[m][n] = __builtin_amdgcn_mfma_f32_16x16x32_bf16(af[m][0], bfr[n][0], acc[m][n], 0, 0, 0);
        acc[m][n] = __builtin_amdgcn_mfma_f32_16x16x32_bf16(af[m][1], bfr[n][1], acc[m][n], 0, 0, 0);
      }
    __syncthreads();
  }
  int lq = lane >> 4;
  long hbase = (long)toff[e] * 128;
#pragma unroll
  for (int m = 0; m < 4; m++) {
#pragma unroll
    for (int j = 0; j < 4; j++) {
      long lrow = m0 + wm * 64 + m * 16 + lq * 4 + j;
      if (lrow >= cnt) continue;
      int orow = idxe[lrow];
      float pw = P[(long)orow * NL_ + e];
#pragma unroll
      for (int n = 0; n < 4; n++) {
        long col = n0 + wn * 64 + n * 16 + lr;
        float g = gelu_exact(acc[m][n][j] + eb1[(size_t)e * HE_ + col]);
        Hall[(hbase + lrow) * HE_ + col] = f2bf(g * pw);
      }
    }
  }
}

// ======== grouped sparse expert GEMM2, BK=64 + XOR chunk swizzle ===========
// A = Hall compact rows (K=2048), B = W2t[e][o][k] (ldb=2048, contiguous).
// Scatter: y[orow][col] += acc via HW f32 atomic (4 adds/elt, low contention).
__global__ __launch_bounds__(256, 2) void gemme2_kernel(
    const u16* __restrict__ Hall, const u16* __restrict__ W2t,
    float* __restrict__ y, const int* __restrict__ idx,
    const int* __restrict__ counts, const int* __restrict__ toff) {
  __shared__ __attribute__((aligned(16))) u16 lA[128 * 64];
  __shared__ __attribute__((aligned(16))) u16 lB[128 * 64];
  int tid = threadIdx.x;
  int gid = blockIdx.x;
  int cpx = gridDim.x >> 3;
  gid = (gid & 7) * cpx + (gid >> 3);
  int mt = gid >> 3, nt = gid & 7;
  if (mt >= toff[NL_]) return;
  int e = 0;
#pragma unroll
  for (int f = 1; f < NL_; f++) e += (mt >= toff[f]) ? 1 : 0;
  int cnt = counts[e];
  long m0 = (long)(mt - toff[e]) * 128;
  long n0 = (long)nt * 128;
  const int* idxe = idx + (long)e * B_;
  int wid = tid >> 6, lane = tid & 63;
  int wm = wid >> 1, wn = wid & 1;
  f32x4 acc[4][4];
#pragma unroll
  for (int m = 0; m < 4; m++)
#pragma unroll
    for (int n = 0; n < 4; n++) acc[m][n] = (f32x4){0.f, 0.f, 0.f, 0.f};
  int lr = lane & 15, lkg = lane >> 4;
  const u16* Ab = Hall + ((long)toff[e] * 128 + m0) * HE_;
  const u16* Bb = W2t + ((size_t)e * O_ + n0) * HE_;
  const u16* gA[4]; const u16* gB[4]; int lds_o[4];
#pragma unroll
  for (int i = 0; i < 4; i++) {
    int sidx = tid + i * 256;
    int r = sidx >> 3, j = sidx & 7;
    int so = ((j ^ (r & 7)) << 3);
    gA[i] = Ab + (long)r * HE_ + so;
    gB[i] = Bb + (long)r * HE_ + so;
    lds_o[i] = sidx * 8;
  }
  int foA[4][2], foB[4][2];
#pragma unroll
  for (int m = 0; m < 4; m++) {
    int r = wm * 64 + m * 16 + lr;
#pragma unroll
    for (int kk = 0; kk < 2; kk++)
      foA[m][kk] = r * 128 + ((((kk * 4 + lkg) ^ (r & 7))) << 4);
  }
#pragma unroll
  for (int n = 0; n < 4; n++) {
    int r = wn * 64 + n * 16 + lr;
#pragma unroll
    for (int kk = 0; kk < 2; kk++)
      foB[n][kk] = r * 128 + ((((kk * 4 + lkg) ^ (r & 7))) << 4);
  }
  const char* pa = (const char*)lA;
  const char* pb = (const char*)lB;
  for (int k0 = 0; k0 < HE_; k0 += 64) {
#pragma unroll
    for (int i = 0; i < 4; i++) gload16(gA[i] + k0, &lA[lds_o[i]]);
#pragma unroll
    for (int i = 0; i < 4; i++) gload16(gB[i] + k0, &lB[lds_o[i]]);
    __syncthreads();
    bf16x8 af[4][2], bfr[4][2];
#pragma unroll
    for (int m = 0; m < 4; m++) {
      af[m][0] = *reinterpret_cast<const bf16x8*>(pa + foA[m][0]);
      af[m][1] = *reinterpret_cast<const bf16x8*>(pa + foA[m][1]);
    }
#pragma unroll
    for (int n = 0; n < 4; n++) {
      bfr[n][0] = *reinterpret_cast<const bf16x8*>(pb + foB[n][0]);
      bfr[n][1] = *reinterpret_cast<const bf16x8*>(pb + foB[n][1]);
    }
#pragma unroll
    for (int m = 0; m < 4; m++)
#pragma unroll
      for (int n = 0; n < 4; n++) {
        acc[m][n] = __builtin_amdgcn_mfma_f32_16x16x32_bf16(af[m][0], bfr[n][0], acc[m][n], 0, 0, 0);
        acc[m][n] = __builtin_amdgcn_mfma_f32_16x16x32_bf16(af[m][1], bfr[n][1], acc[m][n], 0, 0, 0);
      }
    __syncthreads();
  }
  int lq = lane >> 4;
#pragma unroll
  for (int m = 0; m < 4; m++) {
#pragma unroll
    for (int j = 0; j < 4; j++) {
      long lrow = m0 + wm * 64 + m * 16 + lq * 4 + j;
      if (lrow >= cnt) continue;
      long orow = idxe[lrow];
#pragma unroll
      for (int n = 0; n < 4; n++) {
        long col = n0 + wn * 64 + n * 16 + lr;
        unsafeAtomicAdd(&y[orow * O_ + col], acc[m][n][j]);
      }
    }
  }
}

extern "C" void kernel_launch(void* const* d_in, const int* in_sizes, int n_in,
                              void* d_out, int out_size, void* d_ws, size_t ws_size,
                              hipStream_t stream) {
  (void)in_sizes; (void)n_in; (void)out_size; (void)ws_size;
  const float* x   = (const float*)d_in[0];
  const float* rW1 = (const float*)d_in[1];
  const float* rb1 = (const float*)d_in[2];
  const float* rW2 = (const float*)d_in[3];
  const float* rb2 = (const float*)d_in[4];
  const float* eW1 = (const float*)d_in[5];
  const float* eb1 = (const float*)d_in[6];
  const float* eW2 = (const float*)d_in[7];
  const float* eb2 = (const float*)d_in[8];
  const int*  topk = (const int*)d_in[9];
  float* y = (float*)d_out;
  float* P = y + (size_t)B_ * O_;   // leaf_probs live in d_out tail

  // ws layout (high-water ~239 MiB, proven to fit in R7):
  char* ws = (char*)d_ws;
  u16*  Xbs = (u16*)ws;                                   // 32 MiB [hi|lo]
  u16*  W1t = (u16*)(ws + 33554432);                      // 32 MiB
  u16*  W2t = (u16*)(ws + 67108864);                      // 32 MiB [e][o][k]
  int*  idx    = (int*)(ws + 100663296);                  // 256 KiB
  int*  counts = (int*)(ws + 100925440);                  // 32 B
  int*  toff   = (int*)(ws + 100925504);                  // 36 B
  char* hreg   = ws + 100925952;                          // Hall region
  u16*  Hall = (u16*)hreg;                                // 33792x2048 bf16
  u16*  Wr3  = (u16*)hreg;                                // dead before Hall
  float* H1p = (float*)(hreg + 2097152);                  // dead before Hall

  build_xbs_kernel<<<(B_ * D_) / 1024, 256, 0, stream>>>(x, Xbs);
  build_wr3_kernel<<<(256 * K3_) / 1024, 256, 0, stream>>>(rW1, Wr3);
  // W1t[e][n][k] = eW1[e][k][n]
  transpose_cvt_kernel<<<dim3(HE_ / 64, D_ / 64, NL_), 256, 0, stream>>>(
      eW1, W1t, D_, HE_, D_, (long)D_ * HE_, (long)HE_ * D_);
  // W2t[e][o][h] = eW2[e][h][o]   (per-expert contiguous, ldb = HE_)
  transpose_cvt_kernel<<<dim3(O_ / 64, HE_ / 64, NL_), 256, 0, stream>>>(
      eW2, W2t, HE_, O_, HE_, (long)HE_ * O_, (long)O_ * HE_);
  router_gemm_kernel<<<512, 256, 0, stream>>>(Xbs, Wr3, H1p);
  router_logits_kernel<<<B_ / 256, 256, 0, stream>>>(H1p, rb1, rW2, rb2, topk, P);
  yinit_kernel<<<(B_ * O_) / 1024, 256, 0, stream>>>(P, eb2, y);
  compact_kernel<<<NL_, 256, 0, stream>>>(P, idx, counts);
  tiles_kernel<<<1, 1, 0, stream>>>(counts, toff);

  // grouped sparse expert GEMMs (one dispatch each, full GPU)
  gemme1_kernel<<<MTMAX_ * 16, 256, 0, stream>>>(
      Xbs, W1t, eb1, P, Hall, idx, counts, toff);
  gemme2_kernel<<<MTMAX_ * 8, 256, 0, stream>>>(
      Hall, W2t, y, idx, counts, toff);
}